// Round 3
// baseline (241.233 us; speedup 1.0000x reference)
//
#include <hip/hip_runtime.h>

#define NPTS   16384
#define NDIM   64
#define NBATCH 8
#define TB     1024
#define VPT    16      // NPTS / TB
#define NB     6144    // histogram bins (packed u16 counts, 2 per u32)
#define BPT    6       // NB / TB (even: word-aligned per thread)
#define NW     (NB/2)  // packed words
#define EPSF   0.1f
#define MINS   5
#define NCMAX  512
#define BIGI   0x3fffffff

// LDS swizzle for xs: spread per-thread-contiguous accesses across banks (bijective XOR)
__device__ __forceinline__ int phys(int i) { return i ^ ((i >> 5) & 15); }

__device__ __forceinline__ int binof(float x, float mn, float inv) {
  float fb = (x - mn) * inv;
  int b = (int)fb;
  if (fb < 0.f) b = 0;
  if (b > NB - 1) b = NB - 1;
  return b;
}
__device__ __forceinline__ int pk_get(unsigned w, int odd) {
  return (int)((w >> (odd << 4)) & 0xffffu);
}

// ---------------- transpose (B,N,D) -> (B,D,N) ----------------
__global__ void ktrans(const float* __restrict__ f, float* __restrict__ xt) {
  __shared__ float tile[64][65];
  int blk = blockIdx.x;
  int b   = blk >> 8;
  int n0  = (blk & 255) << 6;
  for (int i = threadIdx.x; i < 64 * 64; i += 256) {
    int n = i >> 6, d = i & 63;
    tile[n][d] = f[((size_t)b * NPTS + n0 + n) * NDIM + d];
  }
  __syncthreads();
  for (int i = threadIdx.x; i < 64 * 64; i += 256) {
    int d = i >> 6, n = i & 63;
    xt[((size_t)b * NDIM + d) * NPTS + n0 + n] = tile[n][d];
  }
}

// forward-scan monoid
struct FS { int h; float f; float l; int li; int c; };
__device__ __forceinline__ FS fsid() { FS r; r.h = 0; r.f = 0.f; r.l = 0.f; r.li = -1; r.c = 0; return r; }
__device__ __forceinline__ FS fscomb(FS a, FS b) {
  FS r;
  r.h  = a.h | b.h;
  r.f  = a.h ? a.f : b.f;
  r.l  = b.h ? b.l : a.l;
  r.li = b.h ? b.li : a.li;
  int gap = (a.h && b.h && ((b.f - a.l) > EPSF)) ? 1 : 0;
  r.c  = a.c + b.c + gap;
  return r;
}

// ---------------- per-(b,d) exact 1-D DBSCAN (2 blocks/CU) ----------------
__global__ void __launch_bounds__(TB, 8) kdbscan(const float* __restrict__ xt,
                                                 short* __restrict__ labels,
                                                 short* __restrict__ labg,
                                                 int* __restrict__ nclg) {
  const int tid  = threadIdx.x;
  const int lane = tid & 63;
  const int wid  = tid >> 6;
  const int bd   = blockIdx.x;
  const float* __restrict__ x = xt + (size_t)bd * NPTS;
  short* __restrict__ lab = labg + (size_t)bd * NPTS;   // labels by sorted position (global, L2-hot)

  __shared__ float xs[NPTS];            // 64 KB (phys-swizzled); histogram aliases this pre-scatter
  __shared__ unsigned offsp[NW];        // 12 KB packed u16 bin offsets
  __shared__ float wmn[16], wmx[16];
  __shared__ unsigned wsum[16];
  __shared__ int   sh[16];  __shared__ float sf[16], sl[16];
  __shared__ int   sli[16]; __shared__ int   sc[16];
  __shared__ int   wri[16]; __shared__ float wrv[16];
  unsigned* histp = (unsigned*)xs;      // NW packed words inside xs (dead before scatter)

  // ---- 1. load + min/max ----
  float v[VPT];
  float mn = INFINITY, mx = -INFINITY;
  #pragma unroll
  for (int s = 0; s < VPT; ++s) {
    v[s] = x[tid + s * TB];
    mn = fminf(mn, v[s]); mx = fmaxf(mx, v[s]);
  }
  for (int d = 1; d < 64; d <<= 1) {
    mn = fminf(mn, __shfl_xor(mn, d));
    mx = fmaxf(mx, __shfl_xor(mx, d));
  }
  if (lane == 0) { wmn[wid] = mn; wmx[wid] = mx; }
  __syncthreads();
  mn = wmn[0]; mx = wmx[0];
  for (int w = 1; w < 16; ++w) { mn = fminf(mn, wmn[w]); mx = fmaxf(mx, wmx[w]); }
  float range = mx - mn;
  float inv = (range > 0.f) ? ((float)NB / range) : 0.f;
  __syncthreads();                       // wmn/wmx consumed before any reuse

  // ---- 2. histogram (packed u16 counts, in xs region) ----
  for (int i = tid; i < NW; i += TB) histp[i] = 0u;
  __syncthreads();
  #pragma unroll
  for (int s = 0; s < VPT; ++s) {
    int b = binof(v[s], mn, inv);
    atomicAdd(&histp[b >> 1], 1u << ((b & 1) << 4));
  }
  __syncthreads();

  // ---- 3. exclusive prefix sum -> offsp = packed bin starts ----
  unsigned loc[BPT];
  unsigned run = 0;
  const int bbase = tid * BPT;
  #pragma unroll
  for (int j = 0; j < BPT; ++j) {
    int b = bbase + j;
    unsigned c = (histp[b >> 1] >> ((b & 1) << 4)) & 0xffffu;
    loc[j] = run; run += c;
  }
  unsigned incl = run;
  for (int d = 1; d < 64; d <<= 1) {
    unsigned u = __shfl_up(incl, d);
    if (lane >= d) incl += u;
  }
  unsigned exc = __shfl_up(incl, 1);
  if (lane == 0) exc = 0u;
  if (lane == 63) wsum[wid] = incl;
  __syncthreads();
  unsigned wb = 0;
  for (int w = 0; w < wid; ++w) wb += wsum[w];
  unsigned tb0 = wb + exc;
  #pragma unroll
  for (int k = 0; k < BPT / 2; ++k) {
    unsigned a = tb0 + loc[2 * k];
    unsigned b2 = tb0 + loc[2 * k + 1];
    offsp[(bbase >> 1) + k] = a | (b2 << 16);
  }
  __syncthreads();

  // ---- 4. scatter into bins (atomic on packed u16; offsp -> bin ends) ----
  int pos[VPT];
  #pragma unroll
  for (int s = 0; s < VPT; ++s) {
    int b = binof(v[s], mn, inv);
    unsigned old = atomicAdd(&offsp[b >> 1], 1u << ((b & 1) << 4));
    int p = pk_get(old, b & 1);
    pos[s] = p;
    xs[phys(p)] = v[s];
  }
  __syncthreads();

  // ---- 5. parallel rank within bin -> exact sorted position ----
  int tgt[VPT];
  #pragma unroll
  for (int s = 0; s < VPT; ++s) {
    int b  = binof(v[s], mn, inv);
    int e0 = pk_get(offsp[b >> 1], b & 1);
    int s0 = b ? pk_get(offsp[(b - 1) >> 1], (b - 1) & 1) : 0;
    float vv = v[s]; int pp = pos[s];
    int r = 0;
    for (int j = s0; j < e0; ++j) {
      float xj = xs[phys(j)];
      r += (xj < vv || (xj == vv && j < pp)) ? 1 : 0;
    }
    tgt[s] = s0 + r;
  }
  __syncthreads();
  // ---- 6. write sorted order ----
  #pragma unroll
  for (int s = 0; s < VPT; ++s) xs[phys(tgt[s])] = v[s];
  __syncthreads();

  // ---- 7. rolling window: core flags + FS seed + backward seed ----
  const int p0 = tid * VPT;
  float wa[9];
  #pragma unroll
  for (int k = 0; k < 9; ++k) {
    int i = p0 - 4 + k;
    wa[k] = (i < 0) ? -INFINITY : xs[phys(i)];
  }
  unsigned coremask = 0u;
  FS ch = fsid();
  int fi = BIGI; float fv = 0.f;
  #pragma unroll
  for (int s = 0; s < VPT; ++s) {
    float xi = wa[4];
    float lo = xi - EPSF, hi = xi + EPSF;
    bool core = false;
    #pragma unroll
    for (int t = 0; t < MINS; ++t)
      core |= (wa[4 - t] >= lo) && (wa[8 - t] <= hi);
    if (core) {
      coremask |= (1u << s);
      if (!ch.h) { ch.h = 1; ch.f = xi; }
      else if ((xi - ch.l) > EPSF) ++ch.c;
      ch.l = xi; ch.li = p0 + s;
      if (fi == BIGI) { fi = p0 + s; fv = xi; }
    }
    #pragma unroll
    for (int k = 0; k < 8; ++k) wa[k] = wa[k + 1];
    int nx = p0 + s + 5;
    wa[8] = (nx < NPTS) ? xs[phys(nx)] : INFINITY;
  }

  // ---- 8. FS block scan ----
  FS cur = ch;
  for (int d = 1; d < 64; d <<= 1) {
    FS u;
    u.h  = __shfl_up(cur.h, d);
    u.f  = __shfl_up(cur.f, d);
    u.l  = __shfl_up(cur.l, d);
    u.li = __shfl_up(cur.li, d);
    u.c  = __shfl_up(cur.c, d);
    FS cmb = fscomb(u, cur);
    if (lane >= d) cur = cmb;
  }
  FS exs;
  exs.h  = __shfl_up(cur.h, 1);
  exs.f  = __shfl_up(cur.f, 1);
  exs.l  = __shfl_up(cur.l, 1);
  exs.li = __shfl_up(cur.li, 1);
  exs.c  = __shfl_up(cur.c, 1);
  if (lane == 0) exs = fsid();
  if (lane == 63) { sh[wid] = cur.h; sf[wid] = cur.f; sl[wid] = cur.l; sli[wid] = cur.li; sc[wid] = cur.c; }
  __syncthreads();
  FS pre = fsid();
  for (int w2 = 0; w2 < wid; ++w2) {
    FS t; t.h = sh[w2]; t.f = sf[w2]; t.l = sl[w2]; t.li = sli[w2]; t.c = sc[w2];
    pre = fscomb(pre, t);
  }
  FS sp = fscomb(pre, exs);

  // ---- 9. forward pass 2: core labels -> lab_g; noise: stash left-core idx ----
  float P  = sp.h ? sp.l  : -INFINITY;
  int   Pi = sp.h ? sp.li : -1;
  int starts = sp.h ? (sp.c + 1) : 0;
  #pragma unroll
  for (int s = 0; s < VPT; ++s) {
    int i = p0 + s;
    if ((coremask >> s) & 1u) {
      float xv = xs[phys(i)];
      if ((xv - P) > EPSF) ++starts;
      P = xv; Pi = i;
      lab[i] = (short)(starts - 1);
    } else {
      lab[i] = (short)Pi;               // temp: left-core idx (-1 = none); only self reads
    }
  }
  if (tid == TB - 1) nclg[bd] = starts;
  __syncthreads();                       // core labels visible block-wide

  // ---- 10. backward block scan: next core (idx,val) ----
  int ri = fi; float rv = fv;
  for (int d = 1; d < 64; d <<= 1) {
    int ui = __shfl_down(ri, d); float uv = __shfl_down(rv, d);
    if (lane < 64 - d && ui < ri) { ri = ui; rv = uv; }
  }
  int rei = __shfl_down(ri, 1); float rev = __shfl_down(rv, 1);
  if (lane == 63) rei = BIGI;
  if (lane == 0) { wri[wid] = ri; wrv[wid] = rv; }
  __syncthreads();
  int Ri = rei; float Rv = rev;
  for (int w2 = wid + 1; w2 < 16; ++w2)
    if (wri[w2] < Ri) { Ri = wri[w2]; Rv = wrv[w2]; }

  // ---- 11. border labels (descending) ----
  #pragma unroll
  for (int s = VPT - 1; s >= 0; --s) {
    int i = p0 + s;
    if ((coremask >> s) & 1u) { Ri = i; Rv = xs[phys(i)]; }
    else {
      float xi = xs[phys(i)];
      int li_ = (int)lab[i];
      float dl = (li_ >= 0) ? (xi - xs[phys(li_)]) : INFINITY;
      float dr = (Ri < NPTS) ? (Rv - xi) : INFINITY;
      short lbv = -1;
      if (fminf(dl, dr) <= EPSF)
        lbv = (dl <= dr) ? lab[li_] : lab[Ri];
      lab[i] = lbv;
    }
  }
  __syncthreads();

  // ---- 12. unsort via tgt; coalesced (b,d,n) label writes ----
  #pragma unroll
  for (int s = 0; s < VPT; ++s)
    labels[(size_t)bd * NPTS + tid + s * TB] = lab[tgt[s]];
}

// ------- per-batch cluster-count prefix + inverse col->(dim,label) map -------
__global__ void koffs(const int* __restrict__ ncl, int* __restrict__ colmap) {
  int lane = threadIdx.x & 63;
  int b    = threadIdx.x >> 6;
  int vcnt = ncl[b * 64 + lane];
  int incl = vcnt;
  for (int d = 1; d < 64; d <<= 1) {
    int u = __shfl_up(incl, d);
    if (lane >= d) incl += u;
  }
  int off = incl - vcnt;
  int* cm = colmap + b * NCMAX;
  for (int k = lane; k < NCMAX; k += 64) cm[k] = -1;
  __syncthreads();
  for (int k = 0; k < vcnt; ++k) {
    int col = off + k;
    if (col < NCMAX) cm[col] = lane | (k << 8);
  }
}

// ---------------- fused zero+scatter: write full output rows ----------------
__global__ void __launch_bounds__(TB) kout(const short* __restrict__ labels,
                                           const int* __restrict__ colmap,
                                           float* __restrict__ out) {
  const int tid  = threadIdx.x;
  const int lane = tid & 63;
  const int wid  = tid >> 6;
  const int b    = blockIdx.x >> 5;
  const int n0   = (blockIdx.x & 31) * 512 + wid * 32;

  int cm[8];
  const int* cmb = colmap + b * NCMAX;
  #pragma unroll
  for (int k = 0; k < 8; ++k) {
    int col = (k < 4) ? (lane * 4 + k) : (256 + lane * 4 + (k - 4));
    cm[k] = cmb[col];
  }
  const short* lb_b = labels + (size_t)b * NDIM * NPTS;

  for (int r = 0; r < 32; ++r) {
    int n = n0 + r;
    float o[8];
    #pragma unroll
    for (int k = 0; k < 8; ++k) {
      int m = cm[k];
      float val = 0.f;
      if (m >= 0) {
        int d  = m & 255;
        int kk = m >> 8;
        val = (lb_b[(size_t)d * NPTS + n] == (short)kk) ? 1.0f : 0.0f;
      }
      o[k] = val;
    }
    float4* op = (float4*)(out + ((size_t)b * NPTS + n) * NCMAX);
    op[lane]      = make_float4(o[0], o[1], o[2], o[3]);
    op[64 + lane] = make_float4(o[4], o[5], o[6], o[7]);
  }
}

extern "C" void kernel_launch(void* const* d_in, const int* in_sizes, int n_in,
                              void* d_out, int out_size, void* d_ws, size_t ws_size,
                              hipStream_t stream) {
  const float* feat = (const float*)d_in[0];
  float* out = (float*)d_out;

  char* ws = (char*)d_ws;
  size_t xt_b   = (size_t)NBATCH * NPTS * NDIM * 4;   // 32 MB
  size_t lbl_b  = (size_t)NBATCH * NPTS * NDIM * 2;   // 16 MB
  float* xt     = (float*)ws;
  short* labels = (short*)(ws + xt_b);
  short* labg   = (short*)(ws + xt_b + lbl_b);        // 16 MB sorted-order label scratch
  int*   ncl    = (int*)(ws + xt_b + 2 * lbl_b);
  int*   colmap = ncl + NBATCH * NDIM;

  ktrans  <<<NBATCH * (NPTS / 64), 256, 0, stream>>>(feat, xt);
  kdbscan <<<NBATCH * NDIM, TB, 0, stream>>>(xt, labels, labg, ncl);
  koffs   <<<1, 512, 0, stream>>>(ncl, colmap);
  kout    <<<NBATCH * 32, TB, 0, stream>>>(labels, colmap, out);
}